// Round 2
// baseline (64.061 us; speedup 1.0000x reference)
//
#include <hip/hip_runtime.h>

#define NSEG 4096

// ---------------- Kernel 1: segment mean-pool into ws ----------------
// Grid: NSEG blocks x 128 threads (2 waves). Wave 0 streams emb_a, wave 1 emb_b.
// Each thread owns 4 consecutive columns; rows unrolled x4 for MLP.
__global__ __launch_bounds__(128, 4) void pool_kernel(
    const float* __restrict__ emb_a,
    const float* __restrict__ emb_b,
    const int*   __restrict__ seg,     // [nrows], sorted
    float*       __restrict__ pooled,  // [NSEG][512] in ws
    int nrows)
{
    const int s = blockIdx.x;
    const int t = threadIdx.x;

    __shared__ int bounds[2];
    if (t < 2) {
        int target = s + t;
        int lo = 0, hi = nrows;
        while (lo < hi) {
            int mid = (lo + hi) >> 1;
            if (seg[mid] < target) lo = mid + 1; else hi = mid;
        }
        bounds[t] = lo;
    }
    __syncthreads();
    const int start = bounds[0];
    const int end   = bounds[1];
    const int cnt   = end - start;

    const float*  base = (t < 64) ? emb_a : emb_b;
    const int     colg = t & 63;
    const float4* src  = reinterpret_cast<const float4*>(base) + colg; // row stride 64 float4

    float4 a0 = make_float4(0.f,0.f,0.f,0.f);
    float4 a1 = make_float4(0.f,0.f,0.f,0.f);
    float4 a2 = make_float4(0.f,0.f,0.f,0.f);
    float4 a3 = make_float4(0.f,0.f,0.f,0.f);

    int r = start;
    for (; r + 4 <= end; r += 4) {
        float4 v0 = src[(size_t)(r + 0) * 64];
        float4 v1 = src[(size_t)(r + 1) * 64];
        float4 v2 = src[(size_t)(r + 2) * 64];
        float4 v3 = src[(size_t)(r + 3) * 64];
        a0.x += v0.x; a0.y += v0.y; a0.z += v0.z; a0.w += v0.w;
        a1.x += v1.x; a1.y += v1.y; a1.z += v1.z; a1.w += v1.w;
        a2.x += v2.x; a2.y += v2.y; a2.z += v2.z; a2.w += v2.w;
        a3.x += v3.x; a3.y += v3.y; a3.z += v3.z; a3.w += v3.w;
    }
    for (; r < end; ++r) {
        float4 v = src[(size_t)r * 64];
        a0.x += v.x; a0.y += v.y; a0.z += v.z; a0.w += v.w;
    }

    const float inv = 1.0f / (float)max(cnt, 1);
    float4 acc;
    acc.x = (a0.x + a1.x + a2.x + a3.x) * inv;
    acc.y = (a0.y + a1.y + a2.y + a3.y) * inv;
    acc.z = (a0.z + a1.z + a2.z + a3.z) * inv;
    acc.w = (a0.w + a1.w + a2.w + a3.w) * inv;

    // pooled row layout: [0,256) = emb_a cols, [256,512) = emb_b cols
    const int cbase = ((t >> 6) << 8) + (colg << 2);
    *reinterpret_cast<float4*>(pooled + (size_t)s * 512 + cbase) = acc;
}

// ---------------- Kernel 2: pooled[4096,512] @ W^T + b -> out[4096,32] ----
// Grid: NSEG/32 = 128 blocks x 256 threads (4 waves). Wave owns 8 segments
// (pooled quads in registers); j-loop reads W rows coalesced along lanes;
// shfl-butterfly reduce; coalesced float4 store via small LDS tile.
__global__ __launch_bounds__(256, 4) void proj_kernel(
    const float* __restrict__ pooled,  // [NSEG][512]
    const float* __restrict__ W,       // [32][512]
    const float* __restrict__ bias,    // [32]
    float*       __restrict__ out)     // [NSEG][32]
{
    const int t    = threadIdx.x;
    const int wave = t >> 6;
    const int lane = t & 63;
    const int segbase = blockIdx.x * 32 + wave * 8;

    __shared__ float tile[1024];  // [4 waves][8 segs][32 j]

    // Load pooled fragments for this wave's 8 segments (coalesced, 2 KB/row).
    float4 p0[8], p1[8];
    #pragma unroll
    for (int s = 0; s < 8; ++s) {
        const float4* row = reinterpret_cast<const float4*>(pooled + (size_t)(segbase + s) * 512);
        p0[s] = row[lane];        // d = 4*lane       (0..255)
        p1[s] = row[64 + lane];   // d = 256+4*lane   (256..511)
    }

    #pragma unroll
    for (int j = 0; j < 32; ++j) {
        const float4* wrow = reinterpret_cast<const float4*>(W + j * 512);
        const float4 w0 = wrow[lane];
        const float4 w1 = wrow[64 + lane];
        float sum[8];
        #pragma unroll
        for (int s = 0; s < 8; ++s) {
            float v = p0[s].x*w0.x + p0[s].y*w0.y + p0[s].z*w0.z + p0[s].w*w0.w
                    + p1[s].x*w1.x + p1[s].y*w1.y + p1[s].z*w1.z + p1[s].w*w1.w;
            v += __shfl_xor(v, 1);
            v += __shfl_xor(v, 2);
            v += __shfl_xor(v, 4);
            v += __shfl_xor(v, 8);
            v += __shfl_xor(v, 16);
            v += __shfl_xor(v, 32);
            sum[s] = v;  // full-wave sum, present in all lanes
        }
        // lane k (k<8) keeps segment k's result (compile-time select chain).
        float myv = (lane==0)?sum[0]:(lane==1)?sum[1]:(lane==2)?sum[2]:(lane==3)?sum[3]:
                    (lane==4)?sum[4]:(lane==5)?sum[5]:(lane==6)?sum[6]:sum[7];
        if (lane < 8) tile[wave*256 + lane*32 + j] = myv + bias[j];
    }
    __syncthreads();

    // tile flat layout == out layout for this block's 32 segments: 4 KB store.
    float4 o = reinterpret_cast<const float4*>(tile)[t];
    reinterpret_cast<float4*>(out + (size_t)blockIdx.x * 1024)[t] = o;
}

// ---------------- Fallback: round-1 fused kernel (if ws too small) --------
__global__ __launch_bounds__(128, 8) void seg_pool_proj_kernel(
    const float* __restrict__ emb_a,
    const float* __restrict__ emb_b,
    const int*   __restrict__ seg,
    const float* __restrict__ W,
    const float* __restrict__ bias,
    float*       __restrict__ out,
    int nrows)
{
    const int s = blockIdx.x;
    const int t = threadIdx.x;
    __shared__ int   bounds[2];
    __shared__ float pooled[512];
    if (t < 2) {
        int target = s + t;
        int lo = 0, hi = nrows;
        while (lo < hi) { int mid = (lo + hi) >> 1; if (seg[mid] < target) lo = mid + 1; else hi = mid; }
        bounds[t] = lo;
    }
    __syncthreads();
    const int start = bounds[0], end = bounds[1];
    const int cnt = end - start;
    const float*  base = (t < 64) ? emb_a : emb_b;
    const int     colg = (t & 63);
    const float4* src  = reinterpret_cast<const float4*>(base) + colg;
    float4 acc = make_float4(0.f, 0.f, 0.f, 0.f);
    for (int r = start; r < end; ++r) {
        float4 v = src[(size_t)r * 64];
        acc.x += v.x; acc.y += v.y; acc.z += v.z; acc.w += v.w;
    }
    const float inv = 1.0f / (float)max(cnt, 1);
    const int cbase = ((t >> 6) << 8) + (colg << 2);
    pooled[cbase + 0] = acc.x * inv;
    pooled[cbase + 1] = acc.y * inv;
    pooled[cbase + 2] = acc.z * inv;
    pooled[cbase + 3] = acc.w * inv;
    __syncthreads();
    const int j  = t >> 2;
    const int d0 = (t & 3) << 7;
    const float4* wrow = reinterpret_cast<const float4*>(W + j * 512 + d0);
    const float4* p4   = reinterpret_cast<const float4*>(pooled + d0);
    float sum = 0.f;
    #pragma unroll
    for (int d = 0; d < 32; ++d) {
        float4 w = wrow[d];
        float4 v = p4[d];
        sum += v.x * w.x + v.y * w.y + v.z * w.z + v.w * w.w;
    }
    sum += __shfl_xor(sum, 1);
    sum += __shfl_xor(sum, 2);
    if ((t & 3) == 0) out[s * 32 + j] = sum + bias[j];
}

extern "C" void kernel_launch(void* const* d_in, const int* in_sizes, int n_in,
                              void* d_out, int out_size, void* d_ws, size_t ws_size,
                              hipStream_t stream) {
    const float* emb_a = (const float*)d_in[0];
    const float* emb_b = (const float*)d_in[1];
    const int*   seg   = (const int*)d_in[2];
    const float* W     = (const float*)d_in[3];
    const float* bias  = (const float*)d_in[4];
    float*       out   = (float*)d_out;
    const int nrows = in_sizes[2];

    const size_t need = (size_t)NSEG * 512 * sizeof(float);  // 8 MB
    if (ws_size >= need) {
        float* pooled = (float*)d_ws;
        pool_kernel<<<NSEG, 128, 0, stream>>>(emb_a, emb_b, seg, pooled, nrows);
        proj_kernel<<<NSEG / 32, 256, 0, stream>>>(pooled, W, bias, out);
    } else {
        seg_pool_proj_kernel<<<NSEG, 128, 0, stream>>>(emb_a, emb_b, seg, W, bias, out, nrows);
    }
}

// Round 3
// 37.955 us; speedup vs baseline: 1.6878x; 1.6878x over previous
//
#include <hip/hip_runtime.h>

#define NSEG 4096

// One block per segment. 128 threads = 2 waves.
// Phase 1: mean-pool rows [lb(s), lb(s+1)) of concat(emb_a,emb_b) -> LDS pooled[512].
//   Wave 0 streams emb_a, wave 1 emb_b; each thread owns 4 consecutive cols (float4),
//   row loop unrolled x4 (4 independent 1KB wave-loads in flight).
// Phase 2: out[s][j] = dot(pooled, W[j]) + b[j].
//   Wave w owns j in [16w, 16w+16): W row read COALESCED along lanes (2 float4
//   wave-loads = 1KB contiguous each), pooled fragment held in registers,
//   6-step butterfly reduce per j (16 independent chains -> ILP).
//   Results gathered in LDS, one coalesced 128B store.
__global__ __launch_bounds__(128, 8) void fused_pool_proj_kernel(
    const float* __restrict__ emb_a,
    const float* __restrict__ emb_b,
    const int*   __restrict__ seg,     // [nrows], sorted ascending
    const float* __restrict__ W,       // [32][512]
    const float* __restrict__ bias,    // [32]
    float*       __restrict__ out,     // [NSEG][32]
    int nrows)
{
    const int s    = blockIdx.x;
    const int t    = threadIdx.x;
    const int wave = t >> 6;
    const int lane = t & 63;

    __shared__ int   bounds[2];
    __shared__ float pooled[512];
    __shared__ float sh_out[32];

    // ---- segment bounds via lower_bound (ids sorted; 16 iters, L1-cached) ----
    if (t < 2) {
        int target = s + t;
        int lo = 0, hi = nrows;
        while (lo < hi) {
            int mid = (lo + hi) >> 1;
            if (seg[mid] < target) lo = mid + 1; else hi = mid;
        }
        bounds[t] = lo;
    }
    __syncthreads();
    const int start = bounds[0];
    const int end   = bounds[1];
    const int cnt   = end - start;

    // ---- Phase 1: pooling ----
    const float*  base = (wave == 0) ? emb_a : emb_b;
    const float4* src  = reinterpret_cast<const float4*>(base) + lane; // row stride = 64 float4

    float4 a0 = make_float4(0.f,0.f,0.f,0.f);
    float4 a1 = make_float4(0.f,0.f,0.f,0.f);
    float4 a2 = make_float4(0.f,0.f,0.f,0.f);
    float4 a3 = make_float4(0.f,0.f,0.f,0.f);

    int r = start;
    for (; r + 4 <= end; r += 4) {
        float4 v0 = src[(size_t)(r + 0) * 64];
        float4 v1 = src[(size_t)(r + 1) * 64];
        float4 v2 = src[(size_t)(r + 2) * 64];
        float4 v3 = src[(size_t)(r + 3) * 64];
        a0.x += v0.x; a0.y += v0.y; a0.z += v0.z; a0.w += v0.w;
        a1.x += v1.x; a1.y += v1.y; a1.z += v1.z; a1.w += v1.w;
        a2.x += v2.x; a2.y += v2.y; a2.z += v2.z; a2.w += v2.w;
        a3.x += v3.x; a3.y += v3.y; a3.z += v3.z; a3.w += v3.w;
    }
    for (; r < end; ++r) {
        float4 v = src[(size_t)r * 64];
        a0.x += v.x; a0.y += v.y; a0.z += v.z; a0.w += v.w;
    }

    const float inv = 1.0f / (float)max(cnt, 1);
    float4 acc;
    acc.x = (a0.x + a1.x + a2.x + a3.x) * inv;
    acc.y = (a0.y + a1.y + a2.y + a3.y) * inv;
    acc.z = (a0.z + a1.z + a2.z + a3.z) * inv;
    acc.w = (a0.w + a1.w + a2.w + a3.w) * inv;

    // pooled row layout: [0,256) = emb_a cols, [256,512) = emb_b cols
    *reinterpret_cast<float4*>(pooled + (wave << 8) + (lane << 2)) = acc;
    __syncthreads();

    // ---- Phase 2: projection ----
    // Pooled fragment in registers: lane covers d=4*lane (p0) and d=256+4*lane (p1).
    const float4* pool4 = reinterpret_cast<const float4*>(pooled);
    const float4  p0 = pool4[lane];        // conflict-free b128
    const float4  p1 = pool4[64 + lane];

    #pragma unroll 4
    for (int jj = 0; jj < 16; ++jj) {
        const int j = (wave << 4) + jj;
        const float4* wrow = reinterpret_cast<const float4*>(W + j * 512);
        const float4  w0 = wrow[lane];       // 1KB contiguous wave-load
        const float4  w1 = wrow[64 + lane];
        float v = p0.x*w0.x + p0.y*w0.y + p0.z*w0.z + p0.w*w0.w
                + p1.x*w1.x + p1.y*w1.y + p1.z*w1.z + p1.w*w1.w;
        v += __shfl_xor(v, 1);
        v += __shfl_xor(v, 2);
        v += __shfl_xor(v, 4);
        v += __shfl_xor(v, 8);
        v += __shfl_xor(v, 16);
        v += __shfl_xor(v, 32);
        if (lane == 0) sh_out[j] = v + bias[j];
    }
    __syncthreads();

    // One coalesced 128B store per block.
    if (t < 32) out[s * 32 + t] = sh_out[t];
}

extern "C" void kernel_launch(void* const* d_in, const int* in_sizes, int n_in,
                              void* d_out, int out_size, void* d_ws, size_t ws_size,
                              hipStream_t stream) {
    const float* emb_a = (const float*)d_in[0];
    const float* emb_b = (const float*)d_in[1];
    const int*   seg   = (const int*)d_in[2];
    const float* W     = (const float*)d_in[3];
    const float* bias  = (const float*)d_in[4];
    float*       out   = (float*)d_out;
    const int nrows = in_sizes[2];

    fused_pool_proj_kernel<<<NSEG, 128, 0, stream>>>(emb_a, emb_b, seg, W, bias, out, nrows);
}